// Round 9
// baseline (205.352 us; speedup 1.0000x reference)
//
#include <hip/hip_runtime.h>
#include <cstdint>
#include <cstddef>

typedef float v2f __attribute__((ext_vector_type(2)));

#define HID 16
#define IN  30

#define FAST_RCP(x) __builtin_amdgcn_rcpf(x)

__device__ __forceinline__ float bperm(int baddr, float v) {
    return __int_as_float(__builtin_amdgcn_ds_bpermute(baddr, __float_as_int(v)));
}
// quad_perm [1,0,3,2] (lane^1) and [2,3,0,1] (lane^2): pure-VALU quad butterfly
__device__ __forceinline__ float dq1(float v) {
    return __int_as_float(__builtin_amdgcn_mov_dpp(__float_as_int(v), 0xB1, 0xF, 0xF, true));
}
__device__ __forceinline__ float dq2(float v) {
    return __int_as_float(__builtin_amdgcn_mov_dpp(__float_as_int(v), 0x4E, 0xF, 0xF, true));
}
#define PKFMA(acc, a, b) asm("v_pk_fma_f32 %0, %1, %2, %0" : "+v"(acc) : "v"(a), "v"(b))
#define PKMUL(d, a, b)   asm("v_pk_mul_f32 %0, %1, %2"     : "=v"(d)   : "v"(a), "v"(b))

// ---------------- counting-sort kernels (bins by length, descending) ----------------
__global__ void k_hist(const int* __restrict__ len, int* __restrict__ hist, int B, int T) {
    int i = blockIdx.x * 256 + threadIdx.x;
    if (i < B) atomicAdd(hist + (T - len[i]), 1);
}
__global__ __launch_bounds__(512) void k_scan(const int* __restrict__ hist, int* __restrict__ off) {
    __shared__ int s[512];
    int t = threadIdx.x;
    int v = hist[t];
    s[t] = v; __syncthreads();
    int acc = v;
    for (int o = 1; o < 512; o <<= 1) {
        int add = (t >= o) ? s[t - o] : 0;
        __syncthreads();
        acc += add; s[t] = acc;
        __syncthreads();
    }
    off[t] = acc - v;   // exclusive prefix
}
__global__ void k_scatter(const int* __restrict__ len, int* __restrict__ off,
                          int* __restrict__ perm, int B, int T) {
    int i = blockIdx.x * 256 + threadIdx.x;
    if (i < B) {
        int b = T - len[i];
        int p = atomicAdd(off + b, 1);
        perm[p] = i;
    }
}

// ---------------- main GRU kernel: 1 wave per block, 1 row per wave ----------------
// lane = 4*j + q : j = hidden index (16), q = k-quarter (4)
// grid = B blocks of 64 threads, sorted desc -> LPT with HW refill.
// x in a 4-deep VGPR prefetch ring; h broadcast via 4 ds_bpermute (known-exact).
__global__ __launch_bounds__(64, 4) void gru_enc_kernel(
    const float* __restrict__ x, const int* __restrict__ lengths,
    const float* __restrict__ w_ih, const float* __restrict__ w_hh,
    const float* __restrict__ b_ih, const float* __restrict__ b_hh,
    const float* __restrict__ fc1w, const float* __restrict__ fc1b,
    const float* __restrict__ fc2w, const float* __restrict__ fc2b,
    const float* __restrict__ fc3w, const float* __restrict__ fc3b,
    float* __restrict__ out, const int* __restrict__ perm,
    int B, int T)
{
    const int lane = threadIdx.x & 63;
    const int q    = lane & 3;            // k-quarter (DPP quad dimension)
    const int j    = lane >> 2;           // hidden index owned

    const int pos = blockIdx.x;
    if (pos >= B) return;

    const int row = perm ? perm[pos] : pos;
    const int len = lengths[row];          // wave-uniform: exactly len steps
    const int lenm1 = len - 1;

    const float L2E = 1.4426950408889634f;
    // exp2-domain pre-scaling: r,z by -log2e; n by 2*log2e
    const float gsc[3] = { -L2E, -L2E, 2.0f * L2E };

    // ---- per-lane weights ----
    // input slice: q<3 -> words q*8+2m, q*8+2m+1
    // q==3 remap (all 8B loads stay inside the 120B step):
    //   m0 -> w24,25  m1 -> w26,27  m2 -> ZERO  m3 -> w28,29
    v2f wih2[3][4];
#pragma unroll
    for (int g = 0; g < 3; ++g) {
        const float* wr = w_ih + (size_t)(g * HID + j) * IN;
#pragma unroll
        for (int m = 0; m < 4; ++m) {
            int p0; bool zer = false;
            if (q < 3) p0 = q * 8 + 2 * m;
            else if (m == 0) p0 = 24;
            else if (m == 1) p0 = 26;
            else if (m == 2) { p0 = 0; zer = true; }
            else p0 = 28;
            v2f t;
            t.x = zer ? 0.0f : wr[p0]     * gsc[g];
            t.y = zer ? 0.0f : wr[p0 + 1] * gsc[g];
            wih2[g][m] = t;
        }
    }
    // hidden slice: k = q*4 .. q*4+3
    v2f whh2[3][2];
#pragma unroll
    for (int g = 0; g < 3; ++g)
#pragma unroll
        for (int m = 0; m < 2; ++m) {
            const float* wr = w_hh + (size_t)(g * HID + j) * HID + q * 4 + 2 * m;
            v2f t; t.x = wr[0] * gsc[g]; t.y = wr[1] * gsc[g];
            whh2[g][m] = t;
        }

    // per-lane bias scalars, added once after the quad reduce
    const float bR  = -L2E * (b_ih[j] + b_hh[j]);
    const float bZ  = -L2E * (b_ih[HID + j] + b_hh[HID + j]);
    const float biN = 2.0f * L2E * b_ih[2 * HID + j];
    const float bhN = 2.0f * L2E * b_hh[2 * HID + j];

    // per-lane x byte offsets (loop-invariant)
    const int voff0 = (q < 3) ? q * 32      : 96;
    const int voff1 = (q < 3) ? q * 32 + 8  : 104;
    const int voff2 = (q < 3) ? q * 32 + 16 : 112;
    const int voff3 = (q < 3) ? q * 32 + 24 : 112;

    const char* xrow = (const char*)(x + (size_t)row * T * IN);

    // bpermute byte addresses: lane needs h_k, k = q*4+m; src lane = 4k
    const int ba0 = (16 * q +  0) << 2;
    const int ba1 = (16 * q +  4) << 2;
    const int ba2 = (16 * q +  8) << 2;
    const int ba3 = (16 * q + 12) << 2;

#define LOADT(XB, tt) do {                                                  \
        const char* p_ = xrow + (size_t)min((tt), lenm1) * (IN * 4);        \
        XB[0] = *(const v2f*)(p_ + voff0);                                  \
        XB[1] = *(const v2f*)(p_ + voff1);                                  \
        XB[2] = *(const v2f*)(p_ + voff2);                                  \
        XB[3] = *(const v2f*)(p_ + voff3);                                  \
    } while (0)

#define STEP(XB) do {                                                       \
        v2f ar, az, an, hn;                                                 \
        PKMUL(ar, wih2[0][0], XB[0]);                                       \
        PKMUL(az, wih2[1][0], XB[0]);                                       \
        PKMUL(an, wih2[2][0], XB[0]);                                       \
        PKFMA(ar, wih2[0][1], XB[1]); PKFMA(az, wih2[1][1], XB[1]);         \
        PKFMA(an, wih2[2][1], XB[1]);                                       \
        PKFMA(ar, wih2[0][2], XB[2]); PKFMA(az, wih2[1][2], XB[2]);         \
        PKFMA(an, wih2[2][2], XB[2]);                                       \
        PKFMA(ar, wih2[0][3], XB[3]); PKFMA(az, wih2[1][3], XB[3]);         \
        PKFMA(an, wih2[2][3], XB[3]);                                       \
        PKMUL(hn, whh2[2][0], hb2[0]); PKFMA(hn, whh2[2][1], hb2[1]);       \
        PKFMA(ar, whh2[0][0], hb2[0]); PKFMA(ar, whh2[0][1], hb2[1]);       \
        PKFMA(az, whh2[1][0], hb2[0]); PKFMA(az, whh2[1][1], hb2[1]);       \
        float pr  = ar.x + ar.y;  pr  += dq1(pr);  pr  += dq2(pr);          \
        float pz  = az.x + az.y;  pz  += dq1(pz);  pz  += dq2(pz);          \
        float pxn = an.x + an.y;  pxn += dq1(pxn); pxn += dq2(pxn);         \
        float phn = hn.x + hn.y;  phn += dq1(phn); phn += dq2(phn);         \
        float rg = FAST_RCP(1.0f + __builtin_exp2f(pr + bR));               \
        float zg = FAST_RCP(1.0f + __builtin_exp2f(pz + bZ));               \
        float yy = fmaf(rg, phn + bhN, pxn + biN);                          \
        float ng = fmaf(-2.0f, FAST_RCP(1.0f + __builtin_exp2f(yy)), 1.0f); \
        h_own = fmaf(zg, h_own - ng, ng);                                   \
        hb2[0].x = bperm(ba0, h_own); hb2[0].y = bperm(ba1, h_own);         \
        hb2[1].x = bperm(ba2, h_own); hb2[1].y = bperm(ba3, h_own);         \
    } while (0)

    v2f hb2[2];
    hb2[0].x = 0.0f; hb2[0].y = 0.0f; hb2[1].x = 0.0f; hb2[1].y = 0.0f;
    float h_own = 0.0f;

    // 4-deep prefetch ring
    v2f X0[4], X1[4], X2[4], X3[4];
    LOADT(X0, 0); LOADT(X1, 1); LOADT(X2, 2); LOADT(X3, 3);

    int t = 0;
    for (; t + 4 <= len; t += 4) {
        STEP(X0); LOADT(X0, t + 4);
        STEP(X1); LOADT(X1, t + 5);
        STEP(X2); LOADT(X2, t + 6);
        STEP(X3); LOADT(X3, t + 7);
    }
    if (t     < len) STEP(X0);
    if (t + 1 < len) STEP(X1);
    if (t + 2 < len) STEP(X2);
    // final h of this row is h_own (each lane holds h_j for its own j)

    // ---- FC head (redundant across lanes; once per row) ----
    float hv[16];
#pragma unroll
    for (int k = 0; k < 16; ++k) hv[k] = __shfl(h_own, 4 * k, 64);

    float e1 = fc1b[j];
#pragma unroll
    for (int k = 0; k < 16; ++k) e1 = fmaf(fc1w[j * HID + k], hv[k], e1);

    float v1[16];
#pragma unroll
    for (int k = 0; k < 16; ++k) v1[k] = fmaxf(__shfl(e1, 4 * k, 64), 0.0f);

    float e2 = fc2b[j];
#pragma unroll
    for (int k = 0; k < 16; ++k) e2 = fmaf(fc2w[j * HID + k], v1[k], e2);

    float v2a[16];
#pragma unroll
    for (int k = 0; k < 16; ++k) v2a[k] = fmaxf(__shfl(e2, 4 * k, 64), 0.0f);

    float e3 = fc3b[j];
#pragma unroll
    for (int k = 0; k < 16; ++k) e3 = fmaf(fc3w[j * HID + k], v2a[k], e3);

    if (q == 0) out[(size_t)row * HID + j] = e3;
}

extern "C" void kernel_launch(void* const* d_in, const int* in_sizes, int n_in,
                              void* d_out, int out_size, void* d_ws, size_t ws_size,
                              hipStream_t stream) {
    const float* x    = (const float*)d_in[0];
    const int*   lens = (const int*)d_in[1];
    const float* w_ih = (const float*)d_in[2];
    const float* w_hh = (const float*)d_in[3];
    const float* b_ih = (const float*)d_in[4];
    const float* b_hh = (const float*)d_in[5];
    const float* fc1w = (const float*)d_in[6];
    const float* fc1b = (const float*)d_in[7];
    const float* fc2w = (const float*)d_in[8];
    const float* fc2b = (const float*)d_in[9];
    const float* fc3w = (const float*)d_in[10];
    const float* fc3b = (const float*)d_in[11];
    float* out = (float*)d_out;

    const int B = in_sizes[1];
    const int T = (int)(in_sizes[0] / ((size_t)B * IN));

    // ws layout (ints): perm[B] | hist[512] | off[512]
    int* wsI = (int*)d_ws;
    const size_t need = ((size_t)B + 1024) * sizeof(int);
    const bool dosort = (ws_size >= need) && (T <= 512) && (T >= 1);
    int* perm = dosort ? wsI : nullptr;
    int* hist = wsI + B;
    int* off  = wsI + B + 512;

    if (dosort) {
        hipMemsetAsync(hist, 0, 512 * sizeof(int), stream);
        k_hist<<<(B + 255) / 256, 256, 0, stream>>>(lens, hist, B, T);
        k_scan<<<1, 512, 0, stream>>>(hist, off);
        k_scatter<<<(B + 255) / 256, 256, 0, stream>>>(lens, off, perm, B, T);
    }

    // 1 wave per block, sorted desc -> LPT scheduling with hardware refill
    gru_enc_kernel<<<B, 64, 0, stream>>>(x, lens, w_ih, w_hh, b_ih, b_hh,
                                         fc1w, fc1b, fc2w, fc2b, fc3w, fc3b,
                                         out, perm, B, T);
}